// Round 3
// baseline (4411.910 us; speedup 1.0000x reference)
//
#include <hip/hip_runtime.h>
#include <hip/hip_bf16.h>

// Problem constants (fixed by reference)
#define NN 4096      // nodes
#define EE 16384     // edges
#define GG 128       // graphs
#define HH 64        // hidden / in_dim
#define EDIM 16      // edge_dim
#define HD 4096      // edge-MLP width = 64*64

// Factorized-algorithm tiling
#define NGROUPS 64       // node groups (64 nodes each)
#define GK 16            // k-chunks
#define KT (HD / GK)     // 256 k per block
#define KS 8             // k per sub-iteration (phase-1 panel = KS*64 = 512 cols)
#define KSUBS (KT / KS)  // 32
#define MAXT 40          // max 16-slot edge tiles per group (realized max ~30)
#define MAXSLOT (MAXT * 16)

typedef __attribute__((ext_vector_type(8))) short short8;
typedef __attribute__((ext_vector_type(4))) float float4v;

static __device__ inline unsigned short f2b(float f) {
    unsigned u = __float_as_uint(f);
    unsigned r = u + 0x7fff + ((u >> 16) & 1);   // RNE
    return (unsigned short)(r >> 16);
}

// ---------------------------------------------------------------------------
// h = relu(ea @ w1 + b1) -> bf16 [EE][HD]
// ---------------------------------------------------------------------------
__global__ void hker(const float* __restrict__ ea, const float* __restrict__ w1,
                     const float* __restrict__ b1, unsigned short* __restrict__ hB) {
    __shared__ float sea[16 * 16];
    const int tid = threadIdx.x;
    const int j = blockIdx.x * 256 + tid;
    const int e0 = blockIdx.y * 16;
    float w[16];
#pragma unroll
    for (int k = 0; k < 16; ++k) w[k] = w1[k * HD + j];
    const float b = b1[j];
    sea[tid] = ea[e0 * EDIM + tid];
    __syncthreads();
#pragma unroll 4
    for (int el = 0; el < 16; ++el) {
        float a = b;
#pragma unroll
        for (int k = 0; k < 16; ++k) a += sea[el * 16 + k] * w[k];
        hB[(size_t)(e0 + el) * HD + j] = f2b(fmaxf(a, 0.f));
    }
}

// ---------------------------------------------------------------------------
// W2q permute: W2q[(ss*512 + o*8 + kk)*64 + i] = bf16(w2[(ss*8+kk)*4096 + i*64 + o])
// One block per k-row. Column index within a ksub panel is o*8+kk (o-major).
// ---------------------------------------------------------------------------
__global__ void wperm(const float* __restrict__ w2, unsigned short* __restrict__ W2q) {
    __shared__ float t[64 * 65];
    const int k = blockIdx.x;
    const int tid = threadIdx.x;
    const int o = tid & 63, r4 = tid >> 6;
#pragma unroll
    for (int it = 0; it < 16; ++it) {
        int i = it * 4 + r4;
        t[i * 65 + o] = w2[(size_t)k * HD + i * 64 + o];
    }
    __syncthreads();
    const int o2 = tid >> 2, q = tid & 3;
    const int ss = k >> 3, kk = k & 7;
    size_t base = ((size_t)(ss * 512 + o2 * 8 + kk)) * 64 + q * 16;
    unsigned int buf[8];
#pragma unroll
    for (int j = 0; j < 8; ++j) {
        unsigned short lo = f2b(t[(q * 16 + 2 * j) * 65 + o2]);
        unsigned short hi = f2b(t[(q * 16 + 2 * j + 1) * 65 + o2]);
        buf[j] = (unsigned int)lo | ((unsigned int)hi << 16);
    }
    uint4 v0 = make_uint4(buf[0], buf[1], buf[2], buf[3]);
    uint4 v1 = make_uint4(buf[4], buf[5], buf[6], buf[7]);
    *(uint4*)(&W2q[base]) = v0;
    *(uint4*)(&W2q[base + 8]) = v1;
}

// ---------------------------------------------------------------------------
// Edge bucketing (structure fixed per launch; rebuilt every call)
// ---------------------------------------------------------------------------
__global__ void count_edges(const int* __restrict__ src, const int* __restrict__ dst,
                            int* __restrict__ cnt_src, float* __restrict__ cnt_dst) {
    const int e = blockIdx.x * 256 + threadIdx.x;
    atomicAdd(&cnt_src[src[e]], 1);
    atomicAdd(&cnt_dst[dst[e]], 1.f);
}

// one block, 64 threads; thread g lays out group g's clusters/tiles/slots
__global__ void build_layout(const int* __restrict__ cnt_src, int* __restrict__ node_slot_base,
                             int* __restrict__ tile_cluster, int* __restrict__ group_ntiles) {
    const int g = threadIdx.x;
    int nt = 0;
    int slot = g * MAXSLOT;
    for (int c = 0; c < 16; ++c) {
        int d = 0;
        for (int j = 0; j < 4; ++j) {
            int n = g * 64 + c * 4 + j;
            node_slot_base[n] = slot + d;
            d += cnt_src[n];
        }
        int tcnt = (d + 15) >> 4;
        if (nt + tcnt > MAXT) tcnt = MAXT - nt;   // safety clamp (never triggers)
        for (int j = 0; j < tcnt; ++j) tile_cluster[g * MAXT + nt + j] = c;
        nt += tcnt;
        slot += tcnt * 16;
    }
    group_ntiles[g] = nt;
}

__global__ void fill_slots(const int* __restrict__ src, const int* __restrict__ dst,
                           int* __restrict__ fill, const int* __restrict__ node_slot_base,
                           int* __restrict__ slot_info) {
    const int e = blockIdx.x * 256 + threadIdx.x;
    const int n = src[e];
    const int pos = atomicAdd(&fill[n], 1);
    const int s = node_slot_base[n] + pos;
    const int g = n >> 6;
    if (s < g * MAXSLOT + MAXSLOT)
        slot_info[s] = e | ((n & 3) << 14) | (dst[e] << 16);
}

// ---------------------------------------------------------------------------
// xb[n,o] = sum_i x[n,i]*b2[i*64+o]  (the +b2 bias term of theta)
// ---------------------------------------------------------------------------
__global__ void xb_ker(const float* __restrict__ xcur, const float* __restrict__ b2,
                       float* __restrict__ xb) {
    const int n = blockIdx.x * 4 + (threadIdx.x >> 6);
    const int o = threadIdx.x & 63;
    float a = 0.f;
#pragma unroll
    for (int i = 0; i < 64; ++i) a += xcur[n * 64 + i] * b2[i * 64 + o];
    xb[n * 64 + o] = a;
}

__global__ void b2scatter(const float* __restrict__ xb, const int* __restrict__ src,
                          const int* __restrict__ dst, float* __restrict__ agg) {
    const int e = blockIdx.x * 4 + (threadIdx.x >> 6);
    const int o = threadIdx.x & 63;
    atomicAdd(&agg[(size_t)dst[e] * 64 + o], xb[(size_t)src[e] * 64 + o]);
}

// ---------------------------------------------------------------------------
// Fused factorized kernel.
//   Phase 1: y[n,k,o] = sum_i xg[n,i]*w2[k,i*64+o]  (MFMA, KS=8 k's at a time)
//   Phase 2: msgacc[slot,o] += h[e, 8k] @ y[src_e, 8k, o]  (MFMA, 4-node
//            clusters packed into K=32), acc in VGPR across whole k-chunk.
//   Flush: atomicAdd into agg[dst_e].
// grid: 1024 blocks, blockIdx = g*16 + kc  (%8 == kc%8 -> k-slice per XCD, L2-resident)
// ---------------------------------------------------------------------------
__global__ __launch_bounds__(512, 2)
void ygemm_msg(const float* __restrict__ xcur, const unsigned short* __restrict__ hB,
               const unsigned short* __restrict__ W2q, const int* __restrict__ slot_info,
               const int* __restrict__ tile_cluster, const int* __restrict__ group_ntiles,
               float* __restrict__ agg) {
    __shared__ __align__(16) unsigned short sA[64 * 72];      // x group, bf16, padded rows
    __shared__ __align__(16) unsigned short sY[16 * 64 * 32]; // y subtile [cl][o][node'][k] 64 KB
    __shared__ __align__(16) unsigned short sT[MAXT * 16 * 32]; // phase-2 A tiles 40 KB
    __shared__ int sMeta[MAXSLOT];
    __shared__ int sTC[MAXT];

    const int bid = blockIdx.x;
    const int g = bid >> 4;
    const int kc = bid & 15;
    const int tid = threadIdx.x;
    const int lane = tid & 63, wave = tid >> 6;
    const int quad = lane >> 4, lm = lane & 15;

    // stage x group (64 nodes x 64 i) as bf16
    {
        const int n = tid >> 3, ib = (tid & 7) * 8;
        const float* xp = xcur + (size_t)(g * 64 + n) * 64 + ib;
        unsigned int b[4];
#pragma unroll
        for (int j = 0; j < 4; ++j) {
            unsigned short lo = f2b(xp[2 * j]), hi = f2b(xp[2 * j + 1]);
            b[j] = (unsigned int)lo | ((unsigned int)hi << 16);
        }
        *(uint4*)(&sA[n * 72 + ib]) = make_uint4(b[0], b[1], b[2], b[3]);
    }
    // zero phase-2 A tiles (empty slots stay zero forever)
    {
        uint4 z = make_uint4(0, 0, 0, 0);
        for (int j = tid; j < MAXT * 16 * 32 / 8; j += 512) *(uint4*)(&sT[j * 8]) = z;
    }
    for (int j = tid; j < MAXSLOT; j += 512) sMeta[j] = slot_info[g * MAXSLOT + j];
    for (int j = tid; j < MAXT; j += 512) sTC[j] = tile_cluster[g * MAXT + j];
    const int ntiles = group_ntiles[g];
    __syncthreads();

    float4v acc2[5][4];
#pragma unroll
    for (int a = 0; a < 5; ++a)
#pragma unroll
        for (int t = 0; t < 4; ++t) {
            acc2[a][t][0] = 0.f; acc2[a][t][1] = 0.f;
            acc2[a][t][2] = 0.f; acc2[a][t][3] = 0.f;
        }

    for (int su = 0; su < KSUBS; ++su) {
        const int ss = kc * KSUBS + su;    // global 8-k panel id (0..511)

        // ---- phase 1: y panel ----
        short8 bf[4][2], af[4][2];
        const size_t pan = (size_t)ss * 512;
#pragma unroll
        for (int tt = 0; tt < 4; ++tt)
#pragma unroll
            for (int q2 = 0; q2 < 2; ++q2) {
                const int col = wave * 64 + tt * 16 + lm;
                bf[tt][q2] = *(const short8*)(&W2q[(pan + col) * 64 + q2 * 32 + quad * 8]);
            }
#pragma unroll
        for (int s = 0; s < 4; ++s)
#pragma unroll
            for (int q2 = 0; q2 < 2; ++q2)
                af[s][q2] = *(const short8*)(&sA[(s * 16 + lm) * 72 + q2 * 32 + quad * 8]);

        float4v a1[4][4];
#pragma unroll
        for (int s = 0; s < 4; ++s)
#pragma unroll
            for (int tt = 0; tt < 4; ++tt) {
                a1[s][tt][0] = 0.f; a1[s][tt][1] = 0.f;
                a1[s][tt][2] = 0.f; a1[s][tt][3] = 0.f;
            }
#pragma unroll
        for (int q2 = 0; q2 < 2; ++q2)
#pragma unroll
            for (int s = 0; s < 4; ++s)
#pragma unroll
                for (int tt = 0; tt < 4; ++tt)
                    a1[s][tt] = __builtin_amdgcn_mfma_f32_16x16x32_bf16(af[s][q2], bf[tt][q2], a1[s][tt], 0, 0, 0);

        // write y subtile: node' = r ^ (cluster&3) swizzle (cluster&3 == quad here)
#pragma unroll
        for (int s = 0; s < 4; ++s)
#pragma unroll
            for (int tt = 0; tt < 4; ++tt) {
                const int col = wave * 64 + tt * 16 + lm;
                const int o = col >> 3, kk = col & 7;
                const int cl = s * 4 + quad;
#pragma unroll
                for (int r = 0; r < 4; ++r) {
                    const int np = r ^ quad;
                    sY[cl * 2048 + o * 32 + np * 8 + kk] = f2b(a1[s][tt][r]);
                }
            }
        __syncthreads();

        // ---- A-build: gather h[e, 8k] into slot rows at swizzled k'-block ----
        const int k0 = ss * 8;
        for (int s_i = tid; s_i < ntiles * 16; s_i += 512) {
            const int info = sMeta[s_i];
            if (info >= 0) {
                const int e = info & 0x3FFF;
                const int nl = (info >> 14) & 3;
                const int c3 = sTC[s_i >> 4] & 3;
                uint4 hv = *(const uint4*)(&hB[(size_t)e * HD + k0]);
                *(uint4*)(&sT[s_i * 32 + ((nl ^ c3) * 8)]) = hv;
            }
        }
        __syncthreads();

        // ---- phase 2: per-cluster MFMA ----
        {
            int ai = 0;
            for (int ti = wave; ti < ntiles; ti += 8, ++ai) {
                const int c = sTC[ti];
                short8 a2 = *(const short8*)(&sT[ti * 512 + lm * 32 + quad * 8]);
#pragma unroll
                for (int ot = 0; ot < 4; ++ot) {
                    short8 b2f = *(const short8*)(&sY[c * 2048 + (ot * 16 + lm) * 32 + quad * 8]);
                    acc2[ai][ot] = __builtin_amdgcn_mfma_f32_16x16x32_bf16(a2, b2f, acc2[ai][ot], 0, 0, 0);
                }
            }
        }
        __syncthreads();
    }

    // ---- flush: atomicAdd into agg[dst] ----
    {
        int ai = 0;
        for (int ti = wave; ti < ntiles; ti += 8, ++ai) {
#pragma unroll
            for (int ot = 0; ot < 4; ++ot) {
#pragma unroll
                for (int r = 0; r < 4; ++r) {
                    const int s_i = ti * 16 + quad * 4 + r;
                    const int info = sMeta[s_i];
                    if (info >= 0) {
                        const int d = info >> 16;
                        atomicAdd(&agg[(size_t)d * 64 + ot * 16 + lm], acc2[ai][ot][r]);
                    }
                }
            }
        }
    }
}

// ---------------------------------------------------------------------------
// x_next = relu(agg/cnt + x @ root + bias)
// ---------------------------------------------------------------------------
__global__ void combine(const float* __restrict__ agg, const float* __restrict__ cnt,
                        const float* __restrict__ xcur, const float* __restrict__ root,
                        const float* __restrict__ bias, float* __restrict__ xn) {
    const int n = blockIdx.x * 4 + (threadIdx.x >> 6);
    const int o = threadIdx.x & 63;
    float a = agg[n * 64 + o] / fmaxf(cnt[n], 1.f);
    float r = bias[o];
#pragma unroll
    for (int i = 0; i < 64; ++i) r += xcur[n * 64 + i] * root[i * 64 + o];
    xn[n * 64 + o] = fmaxf(a + r, 0.f);
}

// ---------------------------------------------------------------------------
// global mean pool
// ---------------------------------------------------------------------------
__global__ void pool_accum(const float* __restrict__ x3, const int* __restrict__ batch,
                           float* __restrict__ pool, float* __restrict__ pcnt) {
    const int n = blockIdx.x * 4 + (threadIdx.x >> 6);
    const int o = threadIdx.x & 63;
    const int gi = batch[n];
    atomicAdd(&pool[gi * 64 + o], x3[n * 64 + o]);
    if (o == 0) atomicAdd(&pcnt[gi], 1.f);
}

__global__ void pool_norm(const float* __restrict__ pool, const float* __restrict__ pcnt,
                          float* __restrict__ out) {
    const int idx = blockIdx.x * 256 + threadIdx.x;
    out[idx] = pool[idx] / fmaxf(pcnt[idx >> 6], 1.f);
}

// ---------------------------------------------------------------------------
extern "C" void kernel_launch(void* const* d_in, const int* in_sizes, int n_in,
                              void* d_out, int out_size, void* d_ws, size_t ws_size,
                              hipStream_t stream) {
    const float* x   = (const float*)d_in[0];
    const int*   ei  = (const int*)d_in[1];
    const float* ea  = (const float*)d_in[2];
    const int*   bat = (const int*)d_in[3];
    const int* srcp = ei;
    const int* dstp = ei + EE;

    char* ws = (char*)d_ws;
    size_t off = 0;
    unsigned short* hB  = (unsigned short*)(ws + off); off += (size_t)EE * HD * 2;   // 128 MB
    unsigned short* W2q = (unsigned short*)(ws + off); off += (size_t)HD * HD * 2;   // 32 MB
    int* slot_info      = (int*)(ws + off); off += (size_t)NGROUPS * MAXSLOT * 4;
    int* tile_cluster   = (int*)(ws + off); off += (size_t)NGROUPS * MAXT * 4;
    int* group_ntiles   = (int*)(ws + off); off += 1024;
    int* node_slot_base = (int*)(ws + off); off += (size_t)NN * 4;
    int* cnt_src        = (int*)(ws + off); off += (size_t)NN * 4;   // zeroed
    int* fillc          = (int*)(ws + off); off += (size_t)NN * 4;   // zeroed (contig w/ cnt_src)
    float* cnt_dst      = (float*)(ws + off); off += (size_t)NN * 4; // zeroed (contig)
    float* agg  = (float*)(ws + off); off += (size_t)NN * 64 * 4;
    float* xb   = (float*)(ws + off); off += (size_t)NN * 64 * 4;
    float* xb0  = (float*)(ws + off); off += (size_t)NN * 64 * 4;
    float* xb1  = (float*)(ws + off); off += (size_t)NN * 64 * 4;
    float* pool = (float*)(ws + off); off += (size_t)GG * 64 * 4;
    float* pcnt = (float*)(ws + off); off += (size_t)GG * 4;

    // ---- bucketing (edge structure fixed; rebuilt each call) ----
    hipMemsetAsync(slot_info, 0xFF, (size_t)NGROUPS * MAXSLOT * 4, stream);   // -1
    hipMemsetAsync(cnt_src, 0, (size_t)NN * 4 * 3, stream);                   // cnt_src+fill+cnt_dst
    count_edges<<<EE / 256, 256, 0, stream>>>(srcp, dstp, cnt_src, cnt_dst);
    build_layout<<<1, 64, 0, stream>>>(cnt_src, node_slot_base, tile_cluster, group_ntiles);
    fill_slots<<<EE / 256, 256, 0, stream>>>(srcp, dstp, fillc, node_slot_base, slot_info);

    const float* xcur = x;
    float* xbufs[2] = {xb0, xb1};

    for (int l = 0; l < 3; ++l) {
        const float* w1   = (const float*)d_in[4 + 6 * l + 0];
        const float* b1   = (const float*)d_in[4 + 6 * l + 1];
        const float* w2   = (const float*)d_in[4 + 6 * l + 2];
        const float* b2   = (const float*)d_in[4 + 6 * l + 3];
        const float* root = (const float*)d_in[4 + 6 * l + 4];
        const float* bias = (const float*)d_in[4 + 6 * l + 5];

        wperm<<<HD, 256, 0, stream>>>(w2, W2q);
        hker<<<dim3(HD / 256, EE / 16), 256, 0, stream>>>(ea, w1, b1, hB);
        xb_ker<<<NN / 4, 256, 0, stream>>>(xcur, b2, xb);
        hipMemsetAsync(agg, 0, (size_t)NN * 64 * 4, stream);
        b2scatter<<<EE / 4, 256, 0, stream>>>(xb, srcp, dstp, agg);
        ygemm_msg<<<NGROUPS * GK, 512, 0, stream>>>(xcur, hB, W2q, slot_info,
                                                    tile_cluster, group_ntiles, agg);
        float* xn = xbufs[l & 1];
        combine<<<NN / 4, 256, 0, stream>>>(agg, cnt_dst, xcur, root, bias, xn);
        xcur = xn;
    }
    hipMemsetAsync(pool, 0, (size_t)GG * 64 * 4 + (size_t)GG * 4, stream); // pool+pcnt contiguous
    pool_accum<<<NN / 4, 256, 0, stream>>>(xcur, bat, pool, pcnt);
    pool_norm<<<GG * 64 / 256, 256, 0, stream>>>(pool, pcnt, (float*)d_out);
}

// Round 4
// 1996.819 us; speedup vs baseline: 2.2095x; 2.2095x over previous
//
#include <hip/hip_runtime.h>
#include <hip/hip_bf16.h>

// Problem constants (fixed by reference)
#define NN 4096      // nodes
#define EE 16384     // edges
#define GG 128       // graphs
#define EDIM 16      // edge_dim
#define HD 4096      // edge-MLP width = 64*64

// Factorized-algorithm tiling
#define NGROUPS 64       // node groups (64 nodes each)
#define GK 8             // k-chunks (one 4MB W2q slice per XCD)
#define KSUBS 64         // 8-k sub-iterations per block (GK*KSUBS*8 = 4096)
#define MAXT 40          // max 16-slot edge tiles per group
#define MAXSLOT (MAXT * 16)
#define MAXTW 5          // max tiles per wave (MAXT / 8 waves)

typedef __attribute__((ext_vector_type(8))) short short8;
typedef __attribute__((ext_vector_type(4))) float float4v;

static __device__ inline unsigned short f2b(float f) {
    unsigned u = __float_as_uint(f);
    unsigned r = u + 0x7fff + ((u >> 16) & 1);   // RNE
    return (unsigned short)(r >> 16);
}

static __device__ inline unsigned pk2(float a, float b) {
    __hip_bfloat162 p = __float22bfloat162_rn(make_float2(a, b));
    return *(unsigned*)&p;
}

// ---------------------------------------------------------------------------
// h = relu(ea @ w1 + b1) -> bf16 [EE][HD]
// ---------------------------------------------------------------------------
__global__ void hker(const float* __restrict__ ea, const float* __restrict__ w1,
                     const float* __restrict__ b1, unsigned short* __restrict__ hB) {
    __shared__ float sea[16 * 16];
    const int tid = threadIdx.x;
    const int j = blockIdx.x * 256 + tid;
    const int e0 = blockIdx.y * 16;
    float w[16];
#pragma unroll
    for (int k = 0; k < 16; ++k) w[k] = w1[k * HD + j];
    const float b = b1[j];
    sea[tid] = ea[e0 * EDIM + tid];
    __syncthreads();
#pragma unroll 4
    for (int el = 0; el < 16; ++el) {
        float a = b;
#pragma unroll
        for (int k = 0; k < 16; ++k) a += sea[el * 16 + k] * w[k];
        hB[(size_t)(e0 + el) * HD + j] = f2b(fmaxf(a, 0.f));
    }
}

// ---------------------------------------------------------------------------
// W2q permute (kk-major cols): W2q[(ss*512 + kk*64 + o)*64 + i]
//   = bf16(w2[(ss*8+kk)*4096 + i*64 + o]);  one block per k-row.
// ---------------------------------------------------------------------------
__global__ void wperm(const float* __restrict__ w2, unsigned short* __restrict__ W2q) {
    __shared__ float t[64 * 65];
    const int k = blockIdx.x;
    const int tid = threadIdx.x;
    const int o = tid & 63, r4 = tid >> 6;
#pragma unroll
    for (int it = 0; it < 16; ++it) {
        int i = it * 4 + r4;
        t[i * 65 + o] = w2[(size_t)k * HD + i * 64 + o];
    }
    __syncthreads();
    const int o2 = tid >> 2, q = tid & 3;
    const int ss = k >> 3, kk = k & 7;
    size_t base = ((size_t)(ss * 512 + kk * 64 + o2)) * 64 + q * 16;
    unsigned int buf[8];
#pragma unroll
    for (int j = 0; j < 8; ++j)
        buf[j] = pk2(t[(q * 16 + 2 * j) * 65 + o2], t[(q * 16 + 2 * j + 1) * 65 + o2]);
    *(uint4*)(&W2q[base]) = make_uint4(buf[0], buf[1], buf[2], buf[3]);
    *(uint4*)(&W2q[base + 8]) = make_uint4(buf[4], buf[5], buf[6], buf[7]);
}

// ---------------------------------------------------------------------------
// Edge bucketing (structure fixed per launch; rebuilt every call)
// ---------------------------------------------------------------------------
__global__ void count_edges(const int* __restrict__ src, const int* __restrict__ dst,
                            int* __restrict__ cnt_src, float* __restrict__ cnt_dst) {
    const int e = blockIdx.x * 256 + threadIdx.x;
    atomicAdd(&cnt_src[src[e]], 1);
    atomicAdd(&cnt_dst[dst[e]], 1.f);
}

__global__ void build_layout(const int* __restrict__ cnt_src, int* __restrict__ node_slot_base,
                             int* __restrict__ tile_cluster, int* __restrict__ group_ntiles) {
    const int g = threadIdx.x;
    int nt = 0;
    int slot = g * MAXSLOT;
    for (int c = 0; c < 16; ++c) {
        int d = 0;
        for (int j = 0; j < 4; ++j) {
            int n = g * 64 + c * 4 + j;
            node_slot_base[n] = slot + d;
            d += cnt_src[n];
        }
        int tcnt = (d + 15) >> 4;
        if (nt + tcnt > MAXT) tcnt = MAXT - nt;   // safety clamp
        for (int j = 0; j < tcnt; ++j) tile_cluster[g * MAXT + nt + j] = c;
        nt += tcnt;
        slot += tcnt * 16;
    }
    group_ntiles[g] = nt;
}

__global__ void fill_slots(const int* __restrict__ src, const int* __restrict__ dst,
                           int* __restrict__ fill, const int* __restrict__ node_slot_base,
                           int* __restrict__ slot_info) {
    const int e = blockIdx.x * 256 + threadIdx.x;
    const int n = src[e];
    const int pos = atomicAdd(&fill[n], 1);
    const int s = node_slot_base[n] + pos;
    const int g = n >> 6;
    if (s < g * MAXSLOT + MAXSLOT)
        slot_info[s] = e | ((n & 3) << 14) | (dst[e] << 16);
}

// ---------------------------------------------------------------------------
// xb[n,o] = sum_i x[n,i]*b2[i*64+o]; then scatter to agg (bias term of theta)
// ---------------------------------------------------------------------------
__global__ void xb_ker(const float* __restrict__ xcur, const float* __restrict__ b2,
                       float* __restrict__ xb) {
    const int n = blockIdx.x * 4 + (threadIdx.x >> 6);
    const int o = threadIdx.x & 63;
    float a = 0.f;
#pragma unroll
    for (int i = 0; i < 64; ++i) a += xcur[n * 64 + i] * b2[i * 64 + o];
    xb[n * 64 + o] = a;
}

__global__ void b2scatter(const float* __restrict__ xb, const int* __restrict__ src,
                          const int* __restrict__ dst, float* __restrict__ agg) {
    const int e = blockIdx.x * 4 + (threadIdx.x >> 6);
    const int o = threadIdx.x & 63;
    atomicAdd(&agg[(size_t)dst[e] * 64 + o], xb[(size_t)src[e] * 64 + o]);
}

// ---------------------------------------------------------------------------
// Fused factorized kernel (registers-only accumulators, no sT, swizzled sY).
//   Phase 1: y[n, k0+kk, o] = sum_i xg[n,i]*w2[k0+kk, i*64+o]  (8 kk per su)
//   Phase 2: acc[slot, o] += sum_kk h[e,k0+kk]*y[src_e,k0+kk,o] via MFMA with
//            k_pack = kk*4 + np (4-node clusters), A gathered 4B/lane from hB.
// grid: NGROUPS*GK = 512 blocks; blockIdx&7 = kc -> XCD-resident W2q slice.
// ---------------------------------------------------------------------------
__global__ __launch_bounds__(512, 2)
void ygemm_msg(const float* __restrict__ xcur, const unsigned short* __restrict__ hB,
               const unsigned short* __restrict__ W2q, const int* __restrict__ slot_info,
               const int* __restrict__ tile_cluster, const int* __restrict__ group_ntiles,
               float* __restrict__ agg) {
    __shared__ __align__(16) unsigned short sA[64 * 72];        // 9 KB
    __shared__ __align__(16) unsigned short sY[64 * 64 * 8];    // 64 KB: unit(clqg,o)

    const int bid = blockIdx.x;
    const int g = bid >> 3;
    const int kc = bid & 7;
    const int tid = threadIdx.x;
    const int lane = tid & 63, wave = tid >> 6;
    const int quad = lane >> 4, lm = lane & 15;

    // stage x group (64 nodes x 64 i) as bf16
    {
        const int n = tid >> 3, ib = (tid & 7) * 8;
        const float* xp = xcur + (size_t)(g * 64 + n) * 64 + ib;
        uint4 w = make_uint4(pk2(xp[0], xp[1]), pk2(xp[2], xp[3]),
                             pk2(xp[4], xp[5]), pk2(xp[6], xp[7]));
        *(uint4*)(&sA[n * 72 + ib]) = w;
    }

    const int ntiles = group_ntiles[g];
    int infoR[MAXTW], tcR[MAXTW];
#pragma unroll
    for (int ai = 0; ai < MAXTW; ++ai) {
        const int ti = wave + ai * 8;
        infoR[ai] = (ti < ntiles) ? slot_info[g * MAXSLOT + ti * 16 + lm] : -1;
        tcR[ai]   = (ti < ntiles) ? tile_cluster[g * MAXT + ti] : 0;
    }

    float4v acc2[MAXTW][4];
#pragma unroll
    for (int a = 0; a < MAXTW; ++a)
#pragma unroll
        for (int t = 0; t < 4; ++t) {
            acc2[a][t][0] = 0.f; acc2[a][t][1] = 0.f;
            acc2[a][t][2] = 0.f; acc2[a][t][3] = 0.f;
        }

    const int qg = wave >> 1, half = wave & 1;
    __syncthreads();

    for (int su = 0; su < KSUBS; ++su) {
        const int ss = kc * KSUBS + su;
        const size_t pan = (size_t)ss * 512;

        // ---- phase 1: y panel (kk = wave), K=64 over two q2 halves ----
        float4v a1[4][4];
#pragma unroll
        for (int s = 0; s < 4; ++s)
#pragma unroll
            for (int tt = 0; tt < 4; ++tt) {
                a1[s][tt][0] = 0.f; a1[s][tt][1] = 0.f;
                a1[s][tt][2] = 0.f; a1[s][tt][3] = 0.f;
            }
#pragma unroll
        for (int q2 = 0; q2 < 2; ++q2) {
            short8 bf[4], af[4];
#pragma unroll
            for (int tt = 0; tt < 4; ++tt)
                bf[tt] = *(const short8*)(&W2q[(pan + wave * 64 + tt * 16 + lm) * 64 + q2 * 32 + quad * 8]);
#pragma unroll
            for (int s = 0; s < 4; ++s)
                af[s] = *(const short8*)(&sA[(s * 16 + lm) * 72 + q2 * 32 + quad * 8]);
#pragma unroll
            for (int s = 0; s < 4; ++s)
#pragma unroll
                for (int tt = 0; tt < 4; ++tt)
                    a1[s][tt] = __builtin_amdgcn_mfma_f32_16x16x32_bf16(af[s], bf[tt], a1[s][tt], 0, 0, 0);
        }

        // write y: unit(clqg, o) = o*64 + (clqg^o); shorts [half*4 + np]
#pragma unroll
        for (int s = 0; s < 4; ++s)
#pragma unroll
            for (int tt = 0; tt < 4; ++tt) {
                const int o = tt * 16 + lm;
                const int clqg = s * 16 + quad * 4 + qg;
                const int base = (o * 64 + (clqg ^ o)) * 8 + half * 4;
                uint2 v;
                v.x = pk2(a1[s][tt][0], a1[s][tt][1]);
                v.y = pk2(a1[s][tt][2], a1[s][tt][3]);
                *(uint2*)(&sY[base]) = v;
            }
        __syncthreads();

        // ---- phase 2: per-tile MFMA, A gathered directly from hB ----
        const int k0 = ss * 8;
#pragma unroll
        for (int ai = 0; ai < MAXTW; ++ai) {
            const int ti = wave + ai * 8;
            if (ti < ntiles) {                       // wave-uniform
                const int info = infoR[ai];
                unsigned hd = 0;
                if (info >= 0)
                    hd = *(const unsigned*)(&hB[(size_t)(info & 0x3FFF) * HD + k0 + quad * 2]);
                const int nl = (info >> 14) & 3;
                const unsigned lo = hd & 0xffffu, hi = hd >> 16;
                unsigned w0 = nl == 0 ? lo : (nl == 1 ? (lo << 16) : 0u);
                unsigned w1 = nl == 2 ? lo : (nl == 3 ? (lo << 16) : 0u);
                unsigned w2v = nl == 0 ? hi : (nl == 1 ? (hi << 16) : 0u);
                unsigned w3 = nl == 2 ? hi : (nl == 3 ? (hi << 16) : 0u);
                uint4 aw = make_uint4(w0, w1, w2v, w3);
                short8 a2 = *(short8*)&aw;
                const int c4 = tcR[ai] * 4 + quad;
#pragma unroll
                for (int ot = 0; ot < 4; ++ot) {
                    const int o = ot * 16 + lm;
                    short8 b2f = *(const short8*)(&sY[(o * 64 + (c4 ^ o)) * 8]);
                    acc2[ai][ot] = __builtin_amdgcn_mfma_f32_16x16x32_bf16(a2, b2f, acc2[ai][ot], 0, 0, 0);
                }
            }
        }
        __syncthreads();
    }

    // ---- flush: atomicAdd into agg[dst] ----
#pragma unroll
    for (int ai = 0; ai < MAXTW; ++ai) {
        const int ti = wave + ai * 8;
        if (ti < ntiles) {
#pragma unroll
            for (int r = 0; r < 4; ++r) {
                const int inf2 = __shfl(infoR[ai], quad * 4 + r, 64);
                if (inf2 >= 0) {
                    const int d = inf2 >> 16;
#pragma unroll
                    for (int ot = 0; ot < 4; ++ot)
                        atomicAdd(&agg[(size_t)d * 64 + ot * 16 + lm], acc2[ai][ot][r]);
                }
            }
        }
    }
}

// ---------------------------------------------------------------------------
// x_next = relu(agg/cnt + x @ root + bias)
// ---------------------------------------------------------------------------
__global__ void combine(const float* __restrict__ agg, const float* __restrict__ cnt,
                        const float* __restrict__ xcur, const float* __restrict__ root,
                        const float* __restrict__ bias, float* __restrict__ xn) {
    const int n = blockIdx.x * 4 + (threadIdx.x >> 6);
    const int o = threadIdx.x & 63;
    float a = agg[n * 64 + o] / fmaxf(cnt[n], 1.f);
    float r = bias[o];
#pragma unroll
    for (int i = 0; i < 64; ++i) r += xcur[n * 64 + i] * root[i * 64 + o];
    xn[n * 64 + o] = fmaxf(a + r, 0.f);
}

// ---------------------------------------------------------------------------
// global mean pool
// ---------------------------------------------------------------------------
__global__ void pool_accum(const float* __restrict__ x3, const int* __restrict__ batch,
                           float* __restrict__ pool, float* __restrict__ pcnt) {
    const int n = blockIdx.x * 4 + (threadIdx.x >> 6);
    const int o = threadIdx.x & 63;
    const int gi = batch[n];
    atomicAdd(&pool[gi * 64 + o], x3[n * 64 + o]);
    if (o == 0) atomicAdd(&pcnt[gi], 1.f);
}

__global__ void pool_norm(const float* __restrict__ pool, const float* __restrict__ pcnt,
                          float* __restrict__ out) {
    const int idx = blockIdx.x * 256 + threadIdx.x;
    out[idx] = pool[idx] / fmaxf(pcnt[idx >> 6], 1.f);
}

// ---------------------------------------------------------------------------
extern "C" void kernel_launch(void* const* d_in, const int* in_sizes, int n_in,
                              void* d_out, int out_size, void* d_ws, size_t ws_size,
                              hipStream_t stream) {
    const float* x   = (const float*)d_in[0];
    const int*   ei  = (const int*)d_in[1];
    const float* ea  = (const float*)d_in[2];
    const int*   bat = (const int*)d_in[3];
    const int* srcp = ei;
    const int* dstp = ei + EE;

    char* ws = (char*)d_ws;
    size_t off = 0;
    unsigned short* hB  = (unsigned short*)(ws + off); off += (size_t)EE * HD * 2;   // 128 MB
    unsigned short* W2q = (unsigned short*)(ws + off); off += (size_t)HD * HD * 2;   // 32 MB
    int* slot_info      = (int*)(ws + off); off += (size_t)NGROUPS * MAXSLOT * 4;
    int* tile_cluster   = (int*)(ws + off); off += (size_t)NGROUPS * MAXT * 4;
    int* group_ntiles   = (int*)(ws + off); off += 1024;
    int* node_slot_base = (int*)(ws + off); off += (size_t)NN * 4;
    int* cnt_src        = (int*)(ws + off); off += (size_t)NN * 4;   // zeroed
    int* fillc          = (int*)(ws + off); off += (size_t)NN * 4;   // zeroed (contig)
    float* cnt_dst      = (float*)(ws + off); off += (size_t)NN * 4; // zeroed (contig)
    float* agg  = (float*)(ws + off); off += (size_t)NN * 64 * 4;
    float* xb   = (float*)(ws + off); off += (size_t)NN * 64 * 4;
    float* xb0  = (float*)(ws + off); off += (size_t)NN * 64 * 4;
    float* xb1  = (float*)(ws + off); off += (size_t)NN * 64 * 4;
    float* pool = (float*)(ws + off); off += (size_t)GG * 64 * 4;
    float* pcnt = (float*)(ws + off); off += (size_t)GG * 4;

    // ---- bucketing (edge structure fixed; rebuilt each call) ----
    hipMemsetAsync(slot_info, 0xFF, (size_t)NGROUPS * MAXSLOT * 4, stream);   // -1
    hipMemsetAsync(cnt_src, 0, (size_t)NN * 4 * 3, stream);                   // cnt_src+fill+cnt_dst
    count_edges<<<EE / 256, 256, 0, stream>>>(srcp, dstp, cnt_src, cnt_dst);
    build_layout<<<1, 64, 0, stream>>>(cnt_src, node_slot_base, tile_cluster, group_ntiles);
    fill_slots<<<EE / 256, 256, 0, stream>>>(srcp, dstp, fillc, node_slot_base, slot_info);

    const float* xcur = x;
    float* xbufs[2] = {xb0, xb1};

    for (int l = 0; l < 3; ++l) {
        const float* w1   = (const float*)d_in[4 + 6 * l + 0];
        const float* b1   = (const float*)d_in[4 + 6 * l + 1];
        const float* w2   = (const float*)d_in[4 + 6 * l + 2];
        const float* b2   = (const float*)d_in[4 + 6 * l + 3];
        const float* root = (const float*)d_in[4 + 6 * l + 4];
        const float* bias = (const float*)d_in[4 + 6 * l + 5];

        wperm<<<HD, 256, 0, stream>>>(w2, W2q);
        hker<<<dim3(HD / 256, EE / 16), 256, 0, stream>>>(ea, w1, b1, hB);
        xb_ker<<<NN / 4, 256, 0, stream>>>(xcur, b2, xb);
        hipMemsetAsync(agg, 0, (size_t)NN * 64 * 4, stream);
        b2scatter<<<EE / 4, 256, 0, stream>>>(xb, srcp, dstp, agg);
        ygemm_msg<<<NGROUPS * GK, 512, 0, stream>>>(xcur, hB, W2q, slot_info,
                                                    tile_cluster, group_ntiles, agg);
        float* xn = xbufs[l & 1];
        combine<<<NN / 4, 256, 0, stream>>>(agg, cnt_dst, xcur, root, bias, xn);
        xcur = xn;
    }
    hipMemsetAsync(pool, 0, (size_t)GG * 64 * 4 + (size_t)GG * 4, stream); // pool+pcnt contiguous
    pool_accum<<<NN / 4, 256, 0, stream>>>(xcur, bat, pool, pcnt);
    pool_norm<<<GG * 64 / 256, 256, 0, stream>>>(pool, pcnt, (float*)d_out);
}

// Round 5
// 1664.463 us; speedup vs baseline: 2.6507x; 1.1997x over previous
//
#include <hip/hip_runtime.h>
#include <hip/hip_bf16.h>

// Problem constants (fixed by reference)
#define NN 4096      // nodes
#define EE 16384     // edges
#define GG 128       // graphs
#define EDIM 16      // edge_dim
#define HD 4096      // edge-MLP width = 64*64

// Factorized-algorithm tiling
#define NGROUPS 64       // node groups (64 nodes each)
#define GK 8             // k-chunks (one 4MB W2q slice per XCD)
#define KSUBS 64         // 8-k sub-iterations per block
#define MAXT 40          // max 16-slot edge tiles per group
#define MAXSLOT (MAXT * 16)
#define MAXTW 5          // max tiles per wave
#define SYHALF (64 * 64 * 8)

typedef __attribute__((ext_vector_type(8))) short short8;
typedef __attribute__((ext_vector_type(4))) float float4v;

static __device__ inline unsigned short f2b(float f) {
    unsigned u = __float_as_uint(f);
    unsigned r = u + 0x7fff + ((u >> 16) & 1);   // RNE
    return (unsigned short)(r >> 16);
}

static __device__ inline unsigned pk2(float a, float b) {
    __hip_bfloat162 p = __float22bfloat162_rn(make_float2(a, b));
    return *(unsigned*)&p;
}

// ---------------------------------------------------------------------------
// h = relu(ea @ w1 + b1) -> bf16 [EE][HD]
// ---------------------------------------------------------------------------
__global__ void hker(const float* __restrict__ ea, const float* __restrict__ w1,
                     const float* __restrict__ b1, unsigned short* __restrict__ hB) {
    __shared__ float sea[16 * 16];
    const int tid = threadIdx.x;
    const int j = blockIdx.x * 256 + tid;
    const int e0 = blockIdx.y * 16;
    float w[16];
#pragma unroll
    for (int k = 0; k < 16; ++k) w[k] = w1[k * HD + j];
    const float b = b1[j];
    sea[tid] = ea[e0 * EDIM + tid];
    __syncthreads();
#pragma unroll 4
    for (int el = 0; el < 16; ++el) {
        float a = b;
#pragma unroll
        for (int k = 0; k < 16; ++k) a += sea[el * 16 + k] * w[k];
        hB[(size_t)(e0 + el) * HD + j] = f2b(fmaxf(a, 0.f));
    }
}

// ---------------------------------------------------------------------------
// W2q permute (kk-major cols): W2q[(ss*512 + kk*64 + o)*64 + i]
// ---------------------------------------------------------------------------
__global__ void wperm(const float* __restrict__ w2, unsigned short* __restrict__ W2q) {
    __shared__ float t[64 * 65];
    const int k = blockIdx.x;
    const int tid = threadIdx.x;
    const int o = tid & 63, r4 = tid >> 6;
#pragma unroll
    for (int it = 0; it < 16; ++it) {
        int i = it * 4 + r4;
        t[i * 65 + o] = w2[(size_t)k * HD + i * 64 + o];
    }
    __syncthreads();
    const int o2 = tid >> 2, q = tid & 3;
    const int ss = k >> 3, kk = k & 7;
    size_t base = ((size_t)(ss * 512 + kk * 64 + o2)) * 64 + q * 16;
    unsigned int buf[8];
#pragma unroll
    for (int j = 0; j < 8; ++j)
        buf[j] = pk2(t[(q * 16 + 2 * j) * 65 + o2], t[(q * 16 + 2 * j + 1) * 65 + o2]);
    *(uint4*)(&W2q[base]) = make_uint4(buf[0], buf[1], buf[2], buf[3]);
    *(uint4*)(&W2q[base + 8]) = make_uint4(buf[4], buf[5], buf[6], buf[7]);
}

// ---------------------------------------------------------------------------
// Edge bucketing (structure fixed per launch; rebuilt every call)
// ---------------------------------------------------------------------------
__global__ void count_edges(const int* __restrict__ src, const int* __restrict__ dst,
                            int* __restrict__ cnt_src, float* __restrict__ cnt_dst) {
    const int e = blockIdx.x * 256 + threadIdx.x;
    atomicAdd(&cnt_src[src[e]], 1);
    atomicAdd(&cnt_dst[dst[e]], 1.f);
}

__global__ void build_layout(const int* __restrict__ cnt_src, int* __restrict__ node_slot_base,
                             int* __restrict__ tile_cluster, int* __restrict__ group_ntiles) {
    const int g = threadIdx.x;
    int nt = 0;
    int slot = g * MAXSLOT;
    for (int c = 0; c < 16; ++c) {
        int d = 0;
        for (int j = 0; j < 4; ++j) {
            int n = g * 64 + c * 4 + j;
            node_slot_base[n] = slot + d;
            d += cnt_src[n];
        }
        int tcnt = (d + 15) >> 4;
        if (nt + tcnt > MAXT) tcnt = MAXT - nt;   // safety clamp
        for (int j = 0; j < tcnt; ++j) tile_cluster[g * MAXT + nt + j] = c;
        nt += tcnt;
        slot += tcnt * 16;
    }
    group_ntiles[g] = nt;
}

__global__ void fill_slots(const int* __restrict__ src, const int* __restrict__ dst,
                           int* __restrict__ fill, const int* __restrict__ node_slot_base,
                           int* __restrict__ slot_info) {
    const int e = blockIdx.x * 256 + threadIdx.x;
    const int n = src[e];
    const int pos = atomicAdd(&fill[n], 1);
    const int s = node_slot_base[n] + pos;
    const int g = n >> 6;
    if (s < g * MAXSLOT + MAXSLOT)
        slot_info[s] = e | ((n & 3) << 14) | (dst[e] << 16);
}

// ---------------------------------------------------------------------------
// xb[n,o] = sum_i x[n,i]*b2[i*64+o]; then scatter to agg (bias term of theta)
// ---------------------------------------------------------------------------
__global__ void xb_ker(const float* __restrict__ xcur, const float* __restrict__ b2,
                       float* __restrict__ xb) {
    const int n = blockIdx.x * 4 + (threadIdx.x >> 6);
    const int o = threadIdx.x & 63;
    float a = 0.f;
#pragma unroll
    for (int i = 0; i < 64; ++i) a += xcur[n * 64 + i] * b2[i * 64 + o];
    xb[n * 64 + o] = a;
}

__global__ void b2scatter(const float* __restrict__ xb, const int* __restrict__ src,
                          const int* __restrict__ dst, float* __restrict__ agg) {
    const int e = blockIdx.x * 4 + (threadIdx.x >> 6);
    const int o = threadIdx.x & 63;
    atomicAdd(&agg[(size_t)dst[e] * 64 + o], xb[(size_t)src[e] * 64 + o]);
}

// ---------------------------------------------------------------------------
// Fused factorized kernel — single-barrier pipelined K-loop.
//   Phase 1: y[n, k0+kk, o] = sum_i xg[n,i]*w2[k0+kk, i*64+o]  (8 kk per su)
//   Phase 2: acc[slot, o] += sum_kk h[e,k0+kk]*y[src_e,k0+kk,o] via MFMA,
//            k_pack = kk*4 + np.  sY double-buffered; W2q/hB prefetched
//            into registers during phase 2 of the previous su.
// ---------------------------------------------------------------------------
__global__ __launch_bounds__(512, 1)
void ygemm_msg(const float* __restrict__ xcur, const unsigned short* __restrict__ hB,
               const unsigned short* __restrict__ W2q, const int* __restrict__ slot_info,
               const int* __restrict__ tile_cluster, const int* __restrict__ group_ntiles,
               float* __restrict__ agg) {
    __shared__ __align__(16) unsigned short sA[64 * 72];        // 9 KB
    __shared__ __align__(16) unsigned short sY[2 * SYHALF];     // 128 KB, double buffer

    const int bid = blockIdx.x;
    const int g = bid >> 3;
    const int kc = bid & 7;
    const int tid = threadIdx.x;
    const int lane = tid & 63, wave = tid >> 6;
    const int quad = lane >> 4, lm = lane & 15;

    // stage x group (64 nodes x 64 i) as bf16
    {
        const int n = tid >> 3, ib = (tid & 7) * 8;
        const float* xp = xcur + (size_t)(g * 64 + n) * 64 + ib;
        uint4 w = make_uint4(pk2(xp[0], xp[1]), pk2(xp[2], xp[3]),
                             pk2(xp[4], xp[5]), pk2(xp[6], xp[7]));
        *(uint4*)(&sA[n * 72 + ib]) = w;
    }

    const int ntiles = group_ntiles[g];
    int infoR[MAXTW], tcR[MAXTW];
#pragma unroll
    for (int ai = 0; ai < MAXTW; ++ai) {
        const int ti = wave + ai * 8;
        infoR[ai] = (ti < ntiles) ? slot_info[g * MAXSLOT + ti * 16 + lm] : -1;
        tcR[ai]   = (ti < ntiles) ? tile_cluster[g * MAXT + ti] : 0;
    }

    float4v acc2[MAXTW][4];
#pragma unroll
    for (int a = 0; a < MAXTW; ++a)
#pragma unroll
        for (int t = 0; t < 4; ++t) {
            acc2[a][t][0] = 0.f; acc2[a][t][1] = 0.f;
            acc2[a][t][2] = 0.f; acc2[a][t][3] = 0.f;
        }

    const int qg = wave >> 1, half = wave & 1;
    __syncthreads();

    // loop-invariant A-fragments (sA never rewritten)
    short8 af[4][2];
#pragma unroll
    for (int s = 0; s < 4; ++s)
#pragma unroll
        for (int q2 = 0; q2 < 2; ++q2)
            af[s][q2] = *(const short8*)(&sA[(s * 16 + lm) * 72 + q2 * 32 + quad * 8]);

    // preload W2q B-frags and hB gather words for su = 0
    short8 bf[4][2];
    unsigned hd[MAXTW];
    {
        const size_t pan = (size_t)(kc * KSUBS) * 512;
#pragma unroll
        for (int tt = 0; tt < 4; ++tt)
#pragma unroll
            for (int q2 = 0; q2 < 2; ++q2)
                bf[tt][q2] = *(const short8*)(&W2q[(pan + wave * 64 + tt * 16 + lm) * 64 + q2 * 32 + quad * 8]);
        const int k0 = kc * KSUBS * 8;
#pragma unroll
        for (int ai = 0; ai < MAXTW; ++ai) {
            hd[ai] = 0;
            if (wave + ai * 8 < ntiles && infoR[ai] >= 0)
                hd[ai] = *(const unsigned*)(&hB[(size_t)(infoR[ai] & 0x3FFF) * HD + k0 + quad * 2]);
        }
    }

    for (int su = 0; su < KSUBS; ++su) {
        const int ss = kc * KSUBS + su;
        unsigned short* sYp = sY + (su & 1) * SYHALF;

        // ---- phase 1: y panel (kk = wave), s-sequential to cap registers ----
#pragma unroll
        for (int s = 0; s < 4; ++s) {
            float4v a1[4];
#pragma unroll
            for (int tt = 0; tt < 4; ++tt) {
                a1[tt][0] = 0.f; a1[tt][1] = 0.f; a1[tt][2] = 0.f; a1[tt][3] = 0.f;
            }
#pragma unroll
            for (int q2 = 0; q2 < 2; ++q2)
#pragma unroll
                for (int tt = 0; tt < 4; ++tt)
                    a1[tt] = __builtin_amdgcn_mfma_f32_16x16x32_bf16(af[s][q2], bf[tt][q2], a1[tt], 0, 0, 0);
            // write y: unit(clqg, o) = o*64 + (clqg^o); shorts [half*4 + np]
#pragma unroll
            for (int tt = 0; tt < 4; ++tt) {
                const int o = tt * 16 + lm;
                const int clqg = s * 16 + quad * 4 + qg;
                const int base = (o * 64 + (clqg ^ o)) * 8 + half * 4;
                uint2 v;
                v.x = pk2(a1[tt][0], a1[tt][1]);
                v.y = pk2(a1[tt][2], a1[tt][3]);
                *(uint2*)(&sYp[base]) = v;
            }
        }
        __syncthreads();   // the ONLY barrier per su: sY[p] writes visible

        // ---- prefetch next su's W2q / hB (lands during phase 2) ----
        const int sun = (su + 1 < KSUBS) ? su + 1 : su;
        const int ssn = kc * KSUBS + sun;
        short8 bfN[4][2];
        unsigned hdN[MAXTW];
        {
            const size_t pan = (size_t)ssn * 512;
#pragma unroll
            for (int tt = 0; tt < 4; ++tt)
#pragma unroll
                for (int q2 = 0; q2 < 2; ++q2)
                    bfN[tt][q2] = *(const short8*)(&W2q[(pan + wave * 64 + tt * 16 + lm) * 64 + q2 * 32 + quad * 8]);
            const int k0n = ssn * 8;
#pragma unroll
            for (int ai = 0; ai < MAXTW; ++ai) {
                hdN[ai] = 0;
                if (wave + ai * 8 < ntiles && infoR[ai] >= 0)
                    hdN[ai] = *(const unsigned*)(&hB[(size_t)(infoR[ai] & 0x3FFF) * HD + k0n + quad * 2]);
            }
        }

        // ---- phase 2: per-tile MFMA from preloaded hd + sY[p] ----
#pragma unroll
        for (int ai = 0; ai < MAXTW; ++ai) {
            const int ti = wave + ai * 8;
            if (ti < ntiles) {                       // wave-uniform
                const int info = infoR[ai];
                const int nl = (info >> 14) & 3;
                const unsigned lo = hd[ai] & 0xffffu, hi = hd[ai] >> 16;
                unsigned w0 = nl == 0 ? lo : (nl == 1 ? (lo << 16) : 0u);
                unsigned w1 = nl == 2 ? lo : (nl == 3 ? (lo << 16) : 0u);
                unsigned w2v = nl == 0 ? hi : (nl == 1 ? (hi << 16) : 0u);
                unsigned w3 = nl == 2 ? hi : (nl == 3 ? (hi << 16) : 0u);
                uint4 aw = make_uint4(w0, w1, w2v, w3);
                short8 a2 = *(short8*)&aw;
                const int c4 = tcR[ai] * 4 + quad;
#pragma unroll
                for (int ot = 0; ot < 4; ++ot) {
                    const int o = ot * 16 + lm;
                    short8 b2f = *(const short8*)(&sYp[(o * 64 + (c4 ^ o)) * 8]);
                    acc2[ai][ot] = __builtin_amdgcn_mfma_f32_16x16x32_bf16(a2, b2f, acc2[ai][ot], 0, 0, 0);
                }
            }
        }
        // no trailing barrier: next phase 1 writes the other sY buffer

        // rotate prefetched registers
#pragma unroll
        for (int tt = 0; tt < 4; ++tt)
#pragma unroll
            for (int q2 = 0; q2 < 2; ++q2)
                bf[tt][q2] = bfN[tt][q2];
#pragma unroll
        for (int ai = 0; ai < MAXTW; ++ai) hd[ai] = hdN[ai];
    }

    // ---- flush: atomicAdd into agg[dst] ----
#pragma unroll
    for (int ai = 0; ai < MAXTW; ++ai) {
        const int ti = wave + ai * 8;
        if (ti < ntiles) {
#pragma unroll
            for (int r = 0; r < 4; ++r) {
                const int inf2 = __shfl(infoR[ai], quad * 4 + r, 64);
                if (inf2 >= 0) {
                    const int d = inf2 >> 16;
#pragma unroll
                    for (int ot = 0; ot < 4; ++ot)
                        atomicAdd(&agg[(size_t)d * 64 + ot * 16 + lm], acc2[ai][ot][r]);
                }
            }
        }
    }
}

// ---------------------------------------------------------------------------
// x_next = relu(agg/cnt + x @ root + bias)
// ---------------------------------------------------------------------------
__global__ void combine(const float* __restrict__ agg, const float* __restrict__ cnt,
                        const float* __restrict__ xcur, const float* __restrict__ root,
                        const float* __restrict__ bias, float* __restrict__ xn) {
    const int n = blockIdx.x * 4 + (threadIdx.x >> 6);
    const int o = threadIdx.x & 63;
    float a = agg[n * 64 + o] / fmaxf(cnt[n], 1.f);
    float r = bias[o];
#pragma unroll
    for (int i = 0; i < 64; ++i) r += xcur[n * 64 + i] * root[i * 64 + o];
    xn[n * 64 + o] = fmaxf(a + r, 0.f);
}

// ---------------------------------------------------------------------------
// global mean pool
// ---------------------------------------------------------------------------
__global__ void pool_accum(const float* __restrict__ x3, const int* __restrict__ batch,
                           float* __restrict__ pool, float* __restrict__ pcnt) {
    const int n = blockIdx.x * 4 + (threadIdx.x >> 6);
    const int o = threadIdx.x & 63;
    const int gi = batch[n];
    atomicAdd(&pool[gi * 64 + o], x3[n * 64 + o]);
    if (o == 0) atomicAdd(&pcnt[gi], 1.f);
}

__global__ void pool_norm(const float* __restrict__ pool, const float* __restrict__ pcnt,
                          float* __restrict__ out) {
    const int idx = blockIdx.x * 256 + threadIdx.x;
    out[idx] = pool[idx] / fmaxf(pcnt[idx >> 6], 1.f);
}

// ---------------------------------------------------------------------------
extern "C" void kernel_launch(void* const* d_in, const int* in_sizes, int n_in,
                              void* d_out, int out_size, void* d_ws, size_t ws_size,
                              hipStream_t stream) {
    const float* x   = (const float*)d_in[0];
    const int*   ei  = (const int*)d_in[1];
    const float* ea  = (const float*)d_in[2];
    const int*   bat = (const int*)d_in[3];
    const int* srcp = ei;
    const int* dstp = ei + EE;

    char* ws = (char*)d_ws;
    size_t off = 0;
    unsigned short* hB  = (unsigned short*)(ws + off); off += (size_t)EE * HD * 2;   // 128 MB
    unsigned short* W2q = (unsigned short*)(ws + off); off += (size_t)HD * HD * 2;   // 32 MB
    int* slot_info      = (int*)(ws + off); off += (size_t)NGROUPS * MAXSLOT * 4;
    int* tile_cluster   = (int*)(ws + off); off += (size_t)NGROUPS * MAXT * 4;
    int* group_ntiles   = (int*)(ws + off); off += 1024;
    int* node_slot_base = (int*)(ws + off); off += (size_t)NN * 4;
    int* cnt_src        = (int*)(ws + off); off += (size_t)NN * 4;   // zeroed
    int* fillc          = (int*)(ws + off); off += (size_t)NN * 4;   // zeroed (contig)
    float* cnt_dst      = (float*)(ws + off); off += (size_t)NN * 4; // zeroed (contig)
    float* agg  = (float*)(ws + off); off += (size_t)NN * 64 * 4;
    float* xb   = (float*)(ws + off); off += (size_t)NN * 64 * 4;
    float* xb0  = (float*)(ws + off); off += (size_t)NN * 64 * 4;
    float* xb1  = (float*)(ws + off); off += (size_t)NN * 64 * 4;
    float* pool = (float*)(ws + off); off += (size_t)GG * 64 * 4;
    float* pcnt = (float*)(ws + off); off += (size_t)GG * 4;

    // ---- bucketing (edge structure fixed; rebuilt each call) ----
    hipMemsetAsync(slot_info, 0xFF, (size_t)NGROUPS * MAXSLOT * 4, stream);   // -1
    hipMemsetAsync(cnt_src, 0, (size_t)NN * 4 * 3, stream);                   // cnt_src+fill+cnt_dst
    count_edges<<<EE / 256, 256, 0, stream>>>(srcp, dstp, cnt_src, cnt_dst);
    build_layout<<<1, 64, 0, stream>>>(cnt_src, node_slot_base, tile_cluster, group_ntiles);
    fill_slots<<<EE / 256, 256, 0, stream>>>(srcp, dstp, fillc, node_slot_base, slot_info);

    const float* xcur = x;
    float* xbufs[2] = {xb0, xb1};

    for (int l = 0; l < 3; ++l) {
        const float* w1   = (const float*)d_in[4 + 6 * l + 0];
        const float* b1   = (const float*)d_in[4 + 6 * l + 1];
        const float* w2   = (const float*)d_in[4 + 6 * l + 2];
        const float* b2   = (const float*)d_in[4 + 6 * l + 3];
        const float* root = (const float*)d_in[4 + 6 * l + 4];
        const float* bias = (const float*)d_in[4 + 6 * l + 5];

        wperm<<<HD, 256, 0, stream>>>(w2, W2q);
        hker<<<dim3(HD / 256, EE / 16), 256, 0, stream>>>(ea, w1, b1, hB);
        xb_ker<<<NN / 4, 256, 0, stream>>>(xcur, b2, xb);
        hipMemsetAsync(agg, 0, (size_t)NN * 64 * 4, stream);
        b2scatter<<<EE / 4, 256, 0, stream>>>(xb, srcp, dstp, agg);
        ygemm_msg<<<NGROUPS * GK, 512, 0, stream>>>(xcur, hB, W2q, slot_info,
                                                    tile_cluster, group_ntiles, agg);
        float* xn = xbufs[l & 1];
        combine<<<NN / 4, 256, 0, stream>>>(agg, cnt_dst, xcur, root, bias, xn);
        xcur = xn;
    }
    hipMemsetAsync(pool, 0, (size_t)GG * 64 * 4 + (size_t)GG * 4, stream); // pool+pcnt contiguous
    pool_accum<<<NN / 4, 256, 0, stream>>>(xcur, bat, pool, pcnt);
    pool_norm<<<GG * 64 / 256, 256, 0, stream>>>(pool, pcnt, (float*)d_out);
}